// Round 3
// baseline (121.711 us; speedup 1.0000x reference)
//
#include <hip/hip_runtime.h>

// Problem dims (fixed by reference)
#define B_DIM 32
#define N_DIM 4096
#define PATCH_DIM 1024
#define TEXT_DIM 768
#define HIDDEN 512

typedef float f32x4 __attribute__((ext_vector_type(4)));

__device__ __forceinline__ float dot4(f32x4 a, f32x4 b) {
    return a.x * b.x + a.y * b.y + a.z * b.z + a.w * b.w;
}

// ---------------------------------------------------------------------------
// Kernel A: t[b,h] = text[b,:] . W_text[h,:] + b_text[h]
// grid (32 b, 8 h-chunks), 256 threads. One wave per 16 h-values; text row
// (768 floats = 3 f32x4/lane) cached in registers across the h loop.
// ---------------------------------------------------------------------------
__global__ __launch_bounds__(256) void text_proj_kernel(
    const float* __restrict__ text,     // [B, TEXT_DIM]
    const float* __restrict__ W_text,   // [HIDDEN, TEXT_DIM]
    const float* __restrict__ b_text,   // [HIDDEN]
    float* __restrict__ t_out)          // [B, HIDDEN]
{
    const int b    = blockIdx.x;
    const int lane = threadIdx.x & 63;
    const int hbase = blockIdx.y * 64 + (threadIdx.x >> 6) * 16;

    const f32x4* tx4 = (const f32x4*)(text + (size_t)b * TEXT_DIM);
    const f32x4 t0 = tx4[lane], t1 = tx4[lane + 64], t2 = tx4[lane + 128];

    #pragma unroll 2
    for (int i = 0; i < 16; ++i) {
        const int h = hbase + i;
        const f32x4* wr = (const f32x4*)(W_text + (size_t)h * TEXT_DIM);
        float s = dot4(t0, wr[lane]) + dot4(t1, wr[lane + 64])
                + dot4(t2, wr[lane + 128]);
        #pragma unroll
        for (int off = 32; off; off >>= 1)
            s += __shfl_xor(s, off, 64);
        if (lane == 0)
            t_out[(size_t)b * HIDDEN + h] = s + b_text[h];
    }
}

// ---------------------------------------------------------------------------
// Kernel B: v[b,d] = sum_h t[b,h] * W_patch[h,d]; bias[b] = t[b,:].b_patch
// grid (32 b, 4 d-chunks), 256 threads. t[b] staged in LDS; h-loop with 4
// independent accumulators for load ILP. dc==0 blocks also compute bias.
// ---------------------------------------------------------------------------
__global__ __launch_bounds__(256) void fold_kernel(
    const float* __restrict__ t,        // [B, HIDDEN]
    const float* __restrict__ W_patch,  // [HIDDEN, PATCH_DIM]
    const float* __restrict__ b_patch,  // [HIDDEN]
    float* __restrict__ v,              // [B, PATCH_DIM]
    float* __restrict__ bias_out)       // [B]
{
    const int b   = blockIdx.x;
    const int dc  = blockIdx.y;
    const int tid = threadIdx.x;

    __shared__ float t_sh[HIDDEN];
    t_sh[tid]       = t[(size_t)b * HIDDEN + tid];
    t_sh[tid + 256] = t[(size_t)b * HIDDEN + tid + 256];
    __syncthreads();

    const int d = dc * 256 + tid;
    const float* wp = W_patch + d;

    float a0 = 0.f, a1 = 0.f, a2 = 0.f, a3 = 0.f;
    #pragma unroll 4
    for (int h = 0; h < HIDDEN; h += 4) {
        a0 = fmaf(t_sh[h + 0], wp[(size_t)(h + 0) * PATCH_DIM], a0);
        a1 = fmaf(t_sh[h + 1], wp[(size_t)(h + 1) * PATCH_DIM], a1);
        a2 = fmaf(t_sh[h + 2], wp[(size_t)(h + 2) * PATCH_DIM], a2);
        a3 = fmaf(t_sh[h + 3], wp[(size_t)(h + 3) * PATCH_DIM], a3);
    }
    v[(size_t)b * PATCH_DIM + d] = (a0 + a1) + (a2 + a3);

    if (dc == 0) {
        float partial = t_sh[tid] * b_patch[tid]
                      + t_sh[tid + 256] * b_patch[tid + 256];
        #pragma unroll
        for (int off = 32; off; off >>= 1)
            partial += __shfl_xor(partial, off, 64);
        __shared__ float wsum[4];
        if ((tid & 63) == 0) wsum[tid >> 6] = partial;
        __syncthreads();
        if (tid == 0)
            bias_out[b] = (wsum[0] + wsum[1]) + (wsum[2] + wsum[3]);
    }
}

// ---------------------------------------------------------------------------
// Kernel C (dominant, streams 512 MB of patches):
//   scores[b,n] = patches[b,n,:] . v[b,:] + bias[b]
// Exact-fit persistent launch: 1024 blocks x 256 threads with
// __launch_bounds__(256,4) -> VGPR<=128 -> exactly 4 blocks/CU resident on
// 256 CUs. All blocks start together, uniform work, zero tail quantization
// (R2's 2048-block launch at 5 blocks/CU residency ran 1.6 "rounds" = ~80%
// utilization; this was the 100us-vs-81.5us-floor gap).
// Block owns 128 contiguous rows of one b (32 blocks per b); wave owns 32
// rows, processed 4 at a time: 16 nontemporal float4 loads in flight, 4
// independent shuffle-reduce chains, one float4 store per group from lane 0.
// ---------------------------------------------------------------------------
__global__ __launch_bounds__(256, 4) void score_kernel(
    const float* __restrict__ patches,  // [B*N, PATCH_DIM]
    const float* __restrict__ v,        // [B, PATCH_DIM]
    const float* __restrict__ bias,     // [B]
    float* __restrict__ out)            // [B*N]
{
    const int lane = threadIdx.x & 63;
    const int wid  = threadIdx.x >> 6;
    const int bid  = blockIdx.x;          // 0..1023
    const int b    = bid >> 5;            // 32 blocks per b (4096 rows / 128)
    const int row0 = bid * 128 + wid * 32;

    const f32x4* vv = (const f32x4*)(v + (size_t)b * PATCH_DIM);
    const f32x4 v0 = vv[lane], v1 = vv[lane + 64],
                v2 = vv[lane + 128], v3 = vv[lane + 192];
    const float bs = bias[b];

    #pragma unroll 1
    for (int i = 0; i < 32; i += 4) {
        const f32x4* p0 = (const f32x4*)(patches + (size_t)(row0 + i + 0) * PATCH_DIM);
        const f32x4* p1 = (const f32x4*)(patches + (size_t)(row0 + i + 1) * PATCH_DIM);
        const f32x4* p2 = (const f32x4*)(patches + (size_t)(row0 + i + 2) * PATCH_DIM);
        const f32x4* p3 = (const f32x4*)(patches + (size_t)(row0 + i + 3) * PATCH_DIM);

        f32x4 a00 = __builtin_nontemporal_load(p0 + lane);
        f32x4 a01 = __builtin_nontemporal_load(p0 + lane + 64);
        f32x4 a02 = __builtin_nontemporal_load(p0 + lane + 128);
        f32x4 a03 = __builtin_nontemporal_load(p0 + lane + 192);
        f32x4 a10 = __builtin_nontemporal_load(p1 + lane);
        f32x4 a11 = __builtin_nontemporal_load(p1 + lane + 64);
        f32x4 a12 = __builtin_nontemporal_load(p1 + lane + 128);
        f32x4 a13 = __builtin_nontemporal_load(p1 + lane + 192);
        f32x4 a20 = __builtin_nontemporal_load(p2 + lane);
        f32x4 a21 = __builtin_nontemporal_load(p2 + lane + 64);
        f32x4 a22 = __builtin_nontemporal_load(p2 + lane + 128);
        f32x4 a23 = __builtin_nontemporal_load(p2 + lane + 192);
        f32x4 a30 = __builtin_nontemporal_load(p3 + lane);
        f32x4 a31 = __builtin_nontemporal_load(p3 + lane + 64);
        f32x4 a32 = __builtin_nontemporal_load(p3 + lane + 128);
        f32x4 a33 = __builtin_nontemporal_load(p3 + lane + 192);

        float s0 = dot4(a00, v0) + dot4(a01, v1) + dot4(a02, v2) + dot4(a03, v3);
        float s1 = dot4(a10, v0) + dot4(a11, v1) + dot4(a12, v2) + dot4(a13, v3);
        float s2 = dot4(a20, v0) + dot4(a21, v1) + dot4(a22, v2) + dot4(a23, v3);
        float s3 = dot4(a30, v0) + dot4(a31, v1) + dot4(a32, v2) + dot4(a33, v3);

        // 4 independent butterfly chains, interleaved to hide shfl latency
        #pragma unroll
        for (int off = 32; off; off >>= 1) {
            s0 += __shfl_xor(s0, off, 64);
            s1 += __shfl_xor(s1, off, 64);
            s2 += __shfl_xor(s2, off, 64);
            s3 += __shfl_xor(s3, off, 64);
        }

        if (lane == 0) {
            f32x4 o = { s0 + bs, s1 + bs, s2 + bs, s3 + bs };
            *(f32x4*)(out + row0 + i) = o;
        }
    }
}

extern "C" void kernel_launch(void* const* d_in, const int* in_sizes, int n_in,
                              void* d_out, int out_size, void* d_ws, size_t ws_size,
                              hipStream_t stream) {
    const float* patches = (const float*)d_in[0];  // [B, N, PATCH_DIM]
    const float* text    = (const float*)d_in[1];  // [B, TEXT_DIM]
    const float* W_patch = (const float*)d_in[2];  // [HIDDEN, PATCH_DIM]
    const float* b_patch = (const float*)d_in[3];  // [HIDDEN]
    const float* W_text  = (const float*)d_in[4];  // [HIDDEN, TEXT_DIM]
    const float* b_text  = (const float*)d_in[5];  // [HIDDEN]
    float* out = (float*)d_out;                    // [B, N]

    // Workspace layout (floats): t [B*HIDDEN], v [B*PATCH_DIM], bias [B]
    float* t_ws    = (float*)d_ws;
    float* v_ws    = t_ws + B_DIM * HIDDEN;
    float* bias_ws = v_ws + B_DIM * PATCH_DIM;

    text_proj_kernel<<<dim3(B_DIM, 8), 256, 0, stream>>>(text, W_text, b_text, t_ws);
    fold_kernel<<<dim3(B_DIM, 4), 256, 0, stream>>>(t_ws, W_patch, b_patch, v_ws, bias_ws);
    score_kernel<<<1024, 256, 0, stream>>>(patches, v_ws, bias_ws, out);
}